// Round 1
// baseline (274.407 us; speedup 1.0000x reference)
//
#include <hip/hip_runtime.h>
#include <math.h>

#define BB 8192
#define DD 2048
#define BN_EPS 1e-5f

// One wave per row: s[row] = sum_d norm(raw[row,d]) * w[d]
// norm(v) = (v - mu[d]) * inv[d] when use_norm, else v.
__global__ __launch_bounds__(256) void k_dot(
    const float* __restrict__ raw, const float* __restrict__ w,
    const float* __restrict__ mu, const float* __restrict__ inv,
    float* __restrict__ s, int use_norm)
{
    const int lane = threadIdx.x & 63;
    const int wv   = threadIdx.x >> 6;
    const int row  = blockIdx.x * 4 + wv;
    const float* r = raw + (size_t)row * DD;
    float acc = 0.f;
    #pragma unroll
    for (int k = 0; k < DD / 256; ++k) {
        const int idx = lane * 4 + k * 256;
        const float4 rv  = *(const float4*)(r + idx);
        const float4 wv4 = *(const float4*)(w + idx);
        if (use_norm) {
            const float4 m  = *(const float4*)(mu + idx);
            const float4 iv = *(const float4*)(inv + idx);
            acc += (rv.x - m.x) * iv.x * wv4.x
                 + (rv.y - m.y) * iv.y * wv4.y
                 + (rv.z - m.z) * iv.z * wv4.z
                 + (rv.w - m.w) * iv.w * wv4.w;
        } else {
            acc += rv.x * wv4.x + rv.y * wv4.y + rv.z * wv4.z + rv.w * wv4.w;
        }
    }
    #pragma unroll
    for (int off = 32; off; off >>= 1) acc += __shfl_down(acc, off, 64);
    if (lane == 0) s[row] = acc;
}

// out_next[b,d] = x[b,d]*s[b] + bias[d] + norm(raw[b,d]); in-place over raw.
// Also accumulates per-column sum / sumsq partials per block.
__global__ __launch_bounds__(256) void k_upd(
    const float* __restrict__ x, const float* raw,
    const float* __restrict__ bias, const float* __restrict__ s,
    const float* __restrict__ mu, const float* __restrict__ inv,
    float* outbuf, float* __restrict__ partials,
    int rows_per_blk, int use_norm)
{
    const int t  = threadIdx.x;
    const int c0 = t * 8;
    const int row0 = blockIdx.x * rows_per_blk;
    float bv[8], mv[8], iv[8];
    *(float4*)&bv[0] = *(const float4*)(bias + c0);
    *(float4*)&bv[4] = *(const float4*)(bias + c0 + 4);
    if (use_norm) {
        *(float4*)&mv[0] = *(const float4*)(mu + c0);
        *(float4*)&mv[4] = *(const float4*)(mu + c0 + 4);
        *(float4*)&iv[0] = *(const float4*)(inv + c0);
        *(float4*)&iv[4] = *(const float4*)(inv + c0 + 4);
    } else {
        #pragma unroll
        for (int j = 0; j < 8; ++j) { mv[j] = 0.f; iv[j] = 1.f; }
    }
    float sum[8], sq[8];
    #pragma unroll
    for (int j = 0; j < 8; ++j) { sum[j] = 0.f; sq[j] = 0.f; }

    for (int r = 0; r < rows_per_blk; ++r) {
        const size_t base = (size_t)(row0 + r) * DD + c0;
        const float  sv = s[row0 + r];
        float xv[8], rv[8], v[8];
        *(float4*)&xv[0] = *(const float4*)(x + base);
        *(float4*)&xv[4] = *(const float4*)(x + base + 4);
        *(float4*)&rv[0] = *(const float4*)(raw + base);
        *(float4*)&rv[4] = *(const float4*)(raw + base + 4);
        #pragma unroll
        for (int j = 0; j < 8; ++j) {
            v[j] = fmaf(xv[j], sv, bv[j] + (rv[j] - mv[j]) * iv[j]);
            sum[j] += v[j];
            sq[j]   = fmaf(v[j], v[j], sq[j]);
        }
        *(float4*)(outbuf + base)     = *(float4*)&v[0];
        *(float4*)(outbuf + base + 4) = *(float4*)&v[4];
    }
    float* p = partials + (size_t)blockIdx.x * 2 * DD;
    *(float4*)(p + c0)          = *(float4*)&sum[0];
    *(float4*)(p + c0 + 4)      = *(float4*)&sum[4];
    *(float4*)(p + DD + c0)     = *(float4*)&sq[0];
    *(float4*)(p + DD + c0 + 4) = *(float4*)&sq[4];
}

// Stage-A partial reduction: [NB][2*DD] -> [16][2*DD]
__global__ __launch_bounds__(256) void k_stats_a(
    const float* __restrict__ partials, float* __restrict__ mid, int nb_per_pg)
{
    const int pg = blockIdx.x >> 4;       // 16 partial-groups
    const int ec = blockIdx.x & 15;       // 16 entry-chunks of 256
    const int e  = ec * 256 + threadIdx.x;
    const int p0 = pg * nb_per_pg;
    float acc = 0.f;
    for (int p = 0; p < nb_per_pg; ++p)
        acc += partials[(size_t)(p0 + p) * (2 * DD) + e];
    mid[(size_t)pg * (2 * DD) + e] = acc;
}

// Stage-B: [16][2*DD] -> mu[DD], inv[DD]
__global__ __launch_bounds__(256) void k_stats_b(
    const float* __restrict__ mid, float* __restrict__ mu, float* __restrict__ inv)
{
    const int col = blockIdx.x * 256 + threadIdx.x;   // grid = DD/256
    float sum = 0.f, sq = 0.f;
    #pragma unroll
    for (int p = 0; p < 16; ++p) {
        sum += mid[(size_t)p * 2 * DD + col];
        sq  += mid[(size_t)p * 2 * DD + DD + col];
    }
    const float m   = sum / (float)BB;
    float var = sq / (float)BB - m * m;
    var = fmaxf(var, 0.f);
    mu[col]  = m;
    inv[col] = rsqrtf(var + BN_EPS);
}

// Final in-place normalize of d_out.
__global__ __launch_bounds__(256) void k_norm(
    float* __restrict__ out, const float* __restrict__ mu, const float* __restrict__ inv)
{
    const size_t i = ((size_t)blockIdx.x * 256 + threadIdx.x) * 4;
    const int c = (int)(i & (DD - 1));
    float4 v = *(float4*)(out + i);
    const float4 m  = *(const float4*)(mu + c);
    const float4 iv = *(const float4*)(inv + c);
    v.x = (v.x - m.x) * iv.x;
    v.y = (v.y - m.y) * iv.y;
    v.z = (v.z - m.z) * iv.z;
    v.w = (v.w - m.w) * iv.w;
    *(float4*)(out + i) = v;
}

extern "C" void kernel_launch(void* const* d_in, const int* in_sizes, int n_in,
                              void* d_out, int out_size, void* d_ws, size_t ws_size,
                              hipStream_t stream) {
    const float* x  = (const float*)d_in[0];   // [B, D]
    const float* w  = (const float*)d_in[1];   // [4, D]
    const float* bb = (const float*)d_in[2];   // [4, D]
    float* out = (float*)d_out;
    float* ws  = (float*)d_ws;

    // ws layout (floats): s[B] | mu[D] | inv[D] | mid[16*2*D] | partials[NB*2*D]
    float* s_buf    = ws;
    float* mu_buf   = s_buf + BB;
    float* inv_buf  = mu_buf + DD;
    float* mid_buf  = inv_buf + DD;
    float* partials = mid_buf + 16 * 2 * DD;
    const size_t used_bytes = (size_t)(partials - ws) * sizeof(float);

    int NB = 1024;
    while (NB > 16 && used_bytes + (size_t)NB * 2 * DD * sizeof(float) > ws_size)
        NB >>= 1;
    const int rows_per_blk = BB / NB;
    const int nb_per_pg = NB / 16;

    for (int l = 0; l < 4; ++l) {
        const float* raw = (l == 0) ? x : out;
        const int use_norm = (l != 0);
        k_dot<<<BB / 4, 256, 0, stream>>>(raw, w + l * DD, mu_buf, inv_buf, s_buf, use_norm);
        k_upd<<<NB, 256, 0, stream>>>(x, raw, bb + l * DD, s_buf, mu_buf, inv_buf,
                                      out, partials, rows_per_blk, use_norm);
        k_stats_a<<<16 * 16, 256, 0, stream>>>(partials, mid_buf, nb_per_pg);
        k_stats_b<<<DD / 256, 256, 0, stream>>>(mid_buf, mu_buf, inv_buf);
    }
    k_norm<<<(BB * DD / 4) / 256, 256, 0, stream>>>(out, mu_buf, inv_buf);
}